// Round 4
// baseline (2684.713 us; speedup 1.0000x reference)
//
#include <hip/hip_runtime.h>
#include <hip/hip_cooperative_groups.h>
#include <math.h>

namespace cg = cooperative_groups;

// Sizes: B=32 S=512 V=32000 D_IN=512 D_MODEL=2048 HEADS=8 HD=64
//        N_OUT=64 N_ACT=32 M=10 MH=64 T=20

typedef __attribute__((ext_vector_type(8))) short short8v;
typedef __attribute__((ext_vector_type(4))) float f32x4;

__device__ __forceinline__ float sigf(float x) { return 1.0f / (1.0f + __expf(-x)); }
__device__ __forceinline__ float decf(float d) { return __expf(-fminf(fmaxf(d, 0.0f), 15.0f)); }
__device__ __forceinline__ unsigned short bfr(float x) {
    unsigned int u = __float_as_uint(x);
    u += 0x7FFFu + ((u >> 16) & 1u);
    return (unsigned short)(u >> 16);
}
__device__ __forceinline__ float bff(unsigned short u) {
    return __uint_as_float(((unsigned int)u) << 16);
}
__device__ __forceinline__ unsigned int bf2(float lo, float hi) {
    unsigned int ul = __float_as_uint(lo); ul += 0x7FFFu + ((ul >> 16) & 1u);
    unsigned int uh = __float_as_uint(hi); uh += 0x7FFFu + ((uh >> 16) & 1u);
    return (ul >> 16) | (uh & 0xFFFF0000u);
}
#define BLO(u) __uint_as_float((u) << 16)
#define BHI(u) __uint_as_float((u) & 0xFFFF0000u)
__device__ __forceinline__ int SWZ(int byteoff) {
    return byteoff ^ (((byteoff >> 7) & 7) << 4);
}

// ---------------------------------------------------------------------------
// K0: init trace, act (+Ab bf16 act part), aa/ba, ao/bo, stats
// ---------------------------------------------------------------------------
__global__ __launch_bounds__(256) void k0_init(
    const float* __restrict__ st_tr, const float* __restrict__ st_ac,
    const int* __restrict__ iol, const int* __restrict__ ior,
    float* __restrict__ trace, float* __restrict__ act,
    unsigned short* __restrict__ Ab,
    float* __restrict__ aaB, float* __restrict__ baB,
    float* __restrict__ aoB, float* __restrict__ boB, float* __restrict__ stats)
{
    const int i = blockIdx.x * 256 + threadIdx.x;
    if (i < 655360) {
        const int n = i & 2047;
        const int m = (i >> 11) % 10;
        trace[i] = st_tr[n * 10 + m];
    } else if (i < 720896) {
        const int j = i - 655360;
        const int n = j & 2047, b = j >> 11;
        const float v = st_ac[n];
        act[j] = v;
        Ab[b * 2560 + 512 + n] = bfr(v);
    } else if (i < 721920) {
        aaB[i - 720896] = 0.0f;
    } else if (i < 722944) {
        baB[i - 721920] = 0.0f;
    } else if (i < 724992) {
        const int j = i - 722944;
        const int k = j & 63;
        aoB[j] = st_ac[iol[k]] * st_ac[ior[k]];
    } else if (i < 727040) {
        boB[i - 724992] = 1.0f;
    } else if (i < 727104) {
        stats[i - 727040] = 0.0f;
    }
}

// ---------------------------------------------------------------------------
// S1: MFMA bf16 GEMM:  C(16384x1024) = gather(emb,tok)(16384x512) @ WinKV^T
// ---------------------------------------------------------------------------
__global__ __launch_bounds__(256) void s1_kv_mfma(
    const int* __restrict__ tok, const float* __restrict__ emb,
    const float* __restrict__ Win, const float* __restrict__ b_in,
    unsigned short* __restrict__ khb, unsigned short* __restrict__ vhb)
{
    __shared__ alignas(16) unsigned short Al[128 * 64];
    __shared__ alignas(16) unsigned short Bl[128 * 64];
    const int tid = threadIdx.x;
    const int cb = blockIdx.x & 7;
    const int rb = blockIdx.x >> 3;
    const int r0 = rb * 128, c0 = cb * 128;
    int tokrow[8];
#pragma unroll
    for (int j = 0; j < 8; ++j) tokrow[j] = tok[r0 + ((tid + 256 * j) >> 4)];

    const int wid = tid >> 6, lane = tid & 63;
    const int wm = (wid >> 1) * 64, wn = (wid & 1) * 64;
    const int fr = lane & 15;
    const int fkb = (lane >> 4) * 16;
    f32x4 acc[4][4];
#pragma unroll
    for (int i = 0; i < 4; ++i)
#pragma unroll
        for (int j = 0; j < 4; ++j)
#pragma unroll
            for (int e = 0; e < 4; ++e) acc[i][j][e] = 0.0f;

    for (int kt = 0; kt < 512; kt += 64) {
        float4 av[8], bv[8];
#pragma unroll
        for (int j = 0; j < 8; ++j) {
            const int flat = tid + 256 * j;
            const int row = flat >> 4, kq4 = flat & 15;
            av[j] = *(const float4*)(emb + (size_t)tokrow[j] * 512 + kt + kq4 * 4);
            bv[j] = *(const float4*)(Win + (size_t)(512 + c0 + row) * 512 + kt + kq4 * 4);
        }
        __syncthreads();
#pragma unroll
        for (int j = 0; j < 8; ++j) {
            const int flat = tid + 256 * j;
            const int row = flat >> 4, kq4 = flat & 15;
            const int boff = row * 128 + kq4 * 8;
            uint2 pa = { bf2(av[j].x, av[j].y), bf2(av[j].z, av[j].w) };
            uint2 pb = { bf2(bv[j].x, bv[j].y), bf2(bv[j].z, bv[j].w) };
            *(uint2*)((char*)Al + SWZ(boff)) = pa;
            *(uint2*)((char*)Bl + SWZ(boff)) = pb;
        }
        __syncthreads();
#pragma unroll
        for (int ks = 0; ks < 2; ++ks) {
            short8v af[4], bfv[4];
#pragma unroll
            for (int i = 0; i < 4; ++i)
                af[i] = *(const short8v*)((const char*)Al + SWZ((wm + i * 16 + fr) * 128 + ks * 64 + fkb));
#pragma unroll
            for (int j = 0; j < 4; ++j)
                bfv[j] = *(const short8v*)((const char*)Bl + SWZ((wn + j * 16 + fr) * 128 + ks * 64 + fkb));
#pragma unroll
            for (int i = 0; i < 4; ++i)
#pragma unroll
                for (int j = 0; j < 4; ++j)
                    acc[i][j] = __builtin_amdgcn_mfma_f32_16x16x32_bf16(af[i], bfv[j], acc[i][j], 0, 0, 0);
        }
    }
    unsigned short* outbase = (c0 < 512) ? khb : vhb;
    const int ccol = (c0 < 512) ? c0 : (c0 - 512);
#pragma unroll
    for (int j = 0; j < 4; ++j) {
        const int n = wn + j * 16 + fr;
        const float bias = b_in[512 + c0 + n];
#pragma unroll
        for (int i = 0; i < 4; ++i) {
            const int mbase = wm + i * 16 + (lane >> 4) * 4;
#pragma unroll
            for (int rr = 0; rr < 4; ++rr) {
                const int gr = r0 + mbase + rr;
                outbase[(size_t)gr * 512 + ccol + n] = bfr(acc[i][j][rr] + bias);
            }
        }
    }
}

// ---------------------------------------------------------------------------
// S2: Wall[c][0..511] = bf16( Wsyn[c][0:512] @ Wattn_o )   (ldw 2560)
// ---------------------------------------------------------------------------
__global__ __launch_bounds__(256) void s2_wfused(
    const float* __restrict__ Wsyn, const float* __restrict__ Wao,
    unsigned short* __restrict__ Wall)
{
    __shared__ float As[16][68];
    __shared__ float Bs[16][68];
    const int tid = threadIdx.x;
    const int cb = blockIdx.x & 7;
    const int rb = blockIdx.x >> 3;
    const int r0 = rb * 64, c0 = cb * 64;
    const int ra = tid >> 2, kq = tid & 3;
    const int bk = tid >> 4, bq = tid & 15;
    const int tx = tid & 15, ty = tid >> 4;
    float acc[4][4];
#pragma unroll
    for (int i = 0; i < 4; ++i)
#pragma unroll
        for (int j = 0; j < 4; ++j) acc[i][j] = 0.0f;

    for (int kt = 0; kt < 512; kt += 16) {
        const float4 av = *(const float4*)(Wsyn + (size_t)(r0 + ra) * 2560 + kt + kq * 4);
        const float4 bv = *(const float4*)(Wao + (size_t)(kt + bk) * 512 + c0 + bq * 4);
        __syncthreads();
        As[kq*4+0][ra] = av.x; As[kq*4+1][ra] = av.y; As[kq*4+2][ra] = av.z; As[kq*4+3][ra] = av.w;
        *(float4*)&Bs[bk][bq*4] = bv;
        __syncthreads();
#pragma unroll
        for (int kk = 0; kk < 16; ++kk) {
            const float4 a4 = *(const float4*)&As[kk][ty*4];
            const float4 b4 = *(const float4*)&Bs[kk][tx*4];
            const float a[4] = {a4.x, a4.y, a4.z, a4.w};
            const float b[4] = {b4.x, b4.y, b4.z, b4.w};
#pragma unroll
            for (int i = 0; i < 4; ++i)
#pragma unroll
                for (int j = 0; j < 4; ++j) acc[i][j] = fmaf(a[i], b[j], acc[i][j]);
        }
    }
#pragma unroll
    for (int i = 0; i < 4; ++i) {
        const int gr = r0 + ty*4 + i;
        uint2 o = { bf2(acc[i][0], acc[i][1]), bf2(acc[i][2], acc[i][3]) };
        *(uint2*)(Wall + (size_t)gr*2560 + c0 + tx*4) = o;
    }
}

// ---------------------------------------------------------------------------
// S3: bsyn2[c] = bsyn[c] + sum_k battn_o[k] * Wsyn[c][k]
// ---------------------------------------------------------------------------
__global__ __launch_bounds__(256) void s3_bias(
    const float* __restrict__ Wsyn, const float* __restrict__ battn,
    const float* __restrict__ bsyn, float* __restrict__ bsyn2)
{
    const int c = blockIdx.x * 256 + threadIdx.x;
    float s = bsyn[c];
    const float4* wr = (const float4*)(Wsyn + (size_t)c * 2560);
#pragma unroll 4
    for (int k4 = 0; k4 < 128; ++k4) {
        const float4 w = wr[k4];
        const float4 bb = *(const float4*)(battn + k4*4);
        s += w.x*bb.x + w.y*bb.y + w.z*bb.z + w.w*bb.w;
    }
    bsyn2[c] = s;
}

// ---------------------------------------------------------------------------
// S4: Wall[c][512..2559] = bf16(Wsyn[:, 512:2560])
// ---------------------------------------------------------------------------
__global__ __launch_bounds__(256) void s4_convsyn(
    const float* __restrict__ Wsyn, unsigned short* __restrict__ Wall)
{
    const int idx = blockIdx.x * 256 + threadIdx.x;
    const int row = (idx * 4) >> 11, col = (idx * 4) & 2047;
    const float4 v = *(const float4*)(Wsyn + (size_t)row * 2560 + 512 + col);
    uint2 o = { bf2(v.x, v.y), bf2(v.z, v.w) };
    *(uint2*)(Wall + (size_t)row * 2560 + 512 + col) = o;
}

// ---------------------------------------------------------------------------
// S5: NLM weight re-layout for 8-neuron blocks:
//   W1t[(n>>3)*128 + hh][n&7][16] = {W1[m][hh][n] m=0..9, b1[n][hh], 0..}
//   W2t[(n>>3)*64  + hq][n&7][2]
// ---------------------------------------------------------------------------
__global__ __launch_bounds__(256) void s5_convnlm(
    const float* __restrict__ W1, const float* __restrict__ b1,
    const float* __restrict__ W2,
    unsigned short* __restrict__ W1t, unsigned short* __restrict__ W2t)
{
    const int t = blockIdx.x * 256 + threadIdx.x;   // 0..262143
    const int n = t & 2047, hh = t >> 11;
    unsigned short tmp[16];
#pragma unroll
    for (int m = 0; m < 10; ++m) tmp[m] = bfr(W1[(size_t)(m * 128 + hh) * 2048 + n]);
    tmp[10] = bfr(b1[n * 128 + hh]);
    tmp[11] = 0; tmp[12] = 0; tmp[13] = 0; tmp[14] = 0; tmp[15] = 0;
    uint4 lo = { (unsigned)tmp[0] | ((unsigned)tmp[1] << 16), (unsigned)tmp[2] | ((unsigned)tmp[3] << 16),
                 (unsigned)tmp[4] | ((unsigned)tmp[5] << 16), (unsigned)tmp[6] | ((unsigned)tmp[7] << 16) };
    uint4 hi = { (unsigned)tmp[8] | ((unsigned)tmp[9] << 16), (unsigned)tmp[10] | ((unsigned)tmp[11] << 16),
                 (unsigned)tmp[12] | ((unsigned)tmp[13] << 16), (unsigned)tmp[14] | ((unsigned)tmp[15] << 16) };
    const size_t o1 = (((size_t)(n >> 3) * 128 + hh) * 8 + (n & 7)) * 16;
    *(uint4*)(W1t + o1) = lo;
    *(uint4*)(W1t + o1 + 8) = hi;
    if (hh < 64) {
        const unsigned short a = bfr(W2[(size_t)(hh * 2 + 0) * 2048 + n]);
        const unsigned short g = bfr(W2[(size_t)(hh * 2 + 1) * 2048 + n]);
        *(unsigned int*)(W2t + (((size_t)(n >> 3) * 64 + hh) * 8 + (n & 7)) * 2) =
            (unsigned)a | ((unsigned)g << 16);
    }
}

// ---------------------------------------------------------------------------
// KTICK: the whole 20-tick loop as ONE cooperative kernel.
// 256 blocks x 512 threads. Per tick:
//   Phase A (block=(b,h)): EMA, q, qh, scores, softmax, PV -> Ab bf16
//   Phase B (block=n-tile): MFMA synapse GEMM + GLU -> sg, LN stats
//   Phase C (block=8 neurons): LN, trace, NLM -> act (+Ab bf16)
// Tail: block 0 does final o-update + outputs.
// ---------------------------------------------------------------------------
struct TickParams {
    float* act; const float* dec_a; const float* dec_o;
    const int* ial; const int* iar; const int* iol; const int* ior;
    const float* Wq; const float* bq; const float* Win; const float* b_in;
    const unsigned short* khb; const unsigned short* vhb;
    float* aaB; float* baB; float* aoB; float* boB;
    unsigned short* Ab; const unsigned short* Wall; const float* bs2;
    float* sg; float* stats; const float* ln_g; const float* ln_b;
    const unsigned short* W1t; const unsigned short* W2t; const float* b2;
    float* trace; const float* Wout; const float* bout; float* out;
};

__global__ __launch_bounds__(512, 2) void ktick(TickParams p)
{
    cg::grid_group grid = cg::this_grid();
    __shared__ float smem[11904];
    const int tid = threadIdx.x;
    const int bid = blockIdx.x;

    for (int u = 0; u < 20; ++u) {
        // ================= Phase A: attention =================
        {
            const int b = bid >> 3, h = bid & 7;
            float* sync_lds = smem;          // 32
            float* q_lds   = smem + 32;      // 512
            float* qh_lds  = smem + 544;     // 64
            float* khs     = smem + 608;     // 64*65 = 4160
            float* sc      = smem + 4768;    // 512
            float* red     = smem + 5280;    // 16
            float* pvred   = smem + 5296;    // 512

            if (tid < 32) {
                const int j = tid;
                const float ra = decf(p.dec_a[j]);
                const float pa = p.act[b*2048 + p.ial[j]] * p.act[b*2048 + p.iar[j]];
                const float aa = fmaf(ra, p.aaB[(u & 1)*1024 + b*32 + j], pa);
                const float ban = fmaf(ra, p.baB[(u & 1)*1024 + b*32 + j], 1.0f);
                if (h == 0) { p.aaB[((u+1)&1)*1024 + b*32 + j] = aa; p.baB[((u+1)&1)*1024 + b*32 + j] = ban; }
                sync_lds[j] = aa * rsqrtf(ban);
            } else if (tid >= 64 && tid < 128) {
                if (u > 0) {
                    const int j = tid - 64;
                    const float ro = decf(p.dec_o[j]);
                    const float po = p.act[b*2048 + p.iol[j]] * p.act[b*2048 + p.ior[j]];
                    const float ao = fmaf(ro, p.aoB[((u-1)&1)*2048 + b*64 + j], po);
                    const float bo = fmaf(ro, p.boB[((u-1)&1)*2048 + b*64 + j], 1.0f);
                    if (h == 0) { p.aoB[(u&1)*2048 + b*64 + j] = ao; p.boB[(u&1)*2048 + b*64 + j] = bo; }
                }
            } else if (tid >= 128 && tid < 192) {
                if (u > 0 && bid == 0) p.stats[tid - 128] = 0.0f;
            }
            __syncthreads();
            // q[c], one c per thread
            {
                float s = p.bq[tid];
                const float4* wr = (const float4*)(p.Wq + tid*32);
#pragma unroll
                for (int j4 = 0; j4 < 8; ++j4) {
                    const float4 w = wr[j4];
                    const float4 sv = *(const float4*)&sync_lds[j4*4];
                    s += w.x*sv.x + w.y*sv.y + w.z*sv.z + w.w*sv.w;
                }
                q_lds[tid] = s;
            }
            __syncthreads();
            // qh k-split partials
            {
                const int kq = tid & 63, dg = tid >> 6;
                float q8[8];
                {
                    const float4 qa = *(const float4*)&q_lds[kq*8];
                    const float4 qb = *(const float4*)&q_lds[kq*8 + 4];
                    q8[0]=qa.x; q8[1]=qa.y; q8[2]=qa.z; q8[3]=qa.w;
                    q8[4]=qb.x; q8[5]=qb.y; q8[6]=qb.z; q8[7]=qb.w;
                }
                const float* wb2 = p.Win + (size_t)(h*64)*512 + kq*8;
#pragma unroll
                for (int dd = 0; dd < 8; ++dd) {
                    const int d = dg*8 + dd;
                    const float4 w0 = *(const float4*)(wb2 + (size_t)d*512);
                    const float4 w1 = *(const float4*)(wb2 + (size_t)d*512 + 4);
                    khs[d*65 + kq] = w0.x*q8[0] + w0.y*q8[1] + w0.z*q8[2] + w0.w*q8[3]
                                   + w1.x*q8[4] + w1.y*q8[5] + w1.z*q8[6] + w1.w*q8[7];
                }
            }
            __syncthreads();
            if (tid < 64) {
                float s = p.b_in[h*64 + tid];
                const float* pr = &khs[tid*65];
                for (int k2 = 0; k2 < 64; ++k2) s += pr[k2];
                qh_lds[tid] = s;
            }
            // score row per thread
            uint4 stg[8];
            {
                const unsigned short* krow = p.khb + (size_t)(b*512 + tid)*512 + h*64;
#pragma unroll
                for (int ps = 0; ps < 8; ++ps) stg[ps] = *(const uint4*)(krow + ps*8);
            }
            __syncthreads();
            float qv[64];
#pragma unroll
            for (int d4 = 0; d4 < 16; ++d4) {
                const float4 t4 = *(const float4*)&qh_lds[d4*4];
                qv[d4*4+0] = t4.x; qv[d4*4+1] = t4.y; qv[d4*4+2] = t4.z; qv[d4*4+3] = t4.w;
            }
            float sv = 0.0f;
#pragma unroll
            for (int ps = 0; ps < 8; ++ps) {
                sv = fmaf(BLO(stg[ps].x), qv[ps*8+0], sv); sv = fmaf(BHI(stg[ps].x), qv[ps*8+1], sv);
                sv = fmaf(BLO(stg[ps].y), qv[ps*8+2], sv); sv = fmaf(BHI(stg[ps].y), qv[ps*8+3], sv);
                sv = fmaf(BLO(stg[ps].z), qv[ps*8+4], sv); sv = fmaf(BHI(stg[ps].z), qv[ps*8+5], sv);
                sv = fmaf(BLO(stg[ps].w), qv[ps*8+6], sv); sv = fmaf(BHI(stg[ps].w), qv[ps*8+7], sv);
            }
            const float v = sv * 0.125f;
            // softmax over 512
            const int wid = tid >> 6;
            float m = v;
#pragma unroll
            for (int off = 32; off > 0; off >>= 1) m = fmaxf(m, __shfl_xor(m, off));
            if ((tid & 63) == 0) red[wid] = m;
            __syncthreads();
            float mx = red[0];
#pragma unroll
            for (int j = 1; j < 8; ++j) mx = fmaxf(mx, red[j]);
            const float e = __expf(v - mx);
            sc[tid] = e;
            float s = e;
#pragma unroll
            for (int off = 32; off > 0; off >>= 1) s += __shfl_xor(s, off);
            if ((tid & 63) == 0) red[8 + wid] = s;
            __syncthreads();
            float tot = red[8];
#pragma unroll
            for (int j = 1; j < 8; ++j) tot += red[8 + j];
            const float inv = 1.0f / tot;
            // PV
            {
                const int l = tid & 63, w = tid >> 6;
                const unsigned short* vb = p.vhb + (size_t)(b*512 + w*64)*512 + h*64 + l;
                float a3 = 0.0f;
#pragma unroll 16
                for (int si = 0; si < 64; ++si)
                    a3 = fmaf(sc[w*64 + si], bff(vb[(size_t)si*512]), a3);
                pvred[w*64 + l] = a3;
            }
            __syncthreads();
            if (tid < 64) {
                float a = 0.0f;
#pragma unroll
                for (int j = 0; j < 8; ++j) a += pvred[j*64 + tid];
                p.Ab[b*2560 + h*64 + tid] = bfr(a * inv);
            }
        }
        grid.sync();
        // ================= Phase B: synapse MFMA GEMM + GLU =================
        {
            const int c0 = bid * 8;
            const int w = tid >> 6, lane = tid & 63, fr = lane & 15, kq = lane >> 4;
            const int col = (fr < 8) ? (c0 + fr) : (2048 + c0 + fr - 8);
            const unsigned short* wrow = p.Wall + (size_t)col * 2560 + w*320 + kq*8;
            const unsigned short* ar0 = p.Ab + (size_t)fr * 2560 + w*320 + kq*8;
            const unsigned short* ar1 = p.Ab + (size_t)(16 + fr) * 2560 + w*320 + kq*8;
            f32x4 acc0 = {0.f,0.f,0.f,0.f}, acc1 = {0.f,0.f,0.f,0.f};
#pragma unroll
            for (int kk = 0; kk < 10; ++kk) {
                const short8v bfrag = *(const short8v*)(wrow + kk*32);
                const short8v a0f = *(const short8v*)(ar0 + kk*32);
                const short8v a1f = *(const short8v*)(ar1 + kk*32);
                acc0 = __builtin_amdgcn_mfma_f32_16x16x32_bf16(a0f, bfrag, acc0, 0, 0, 0);
                acc1 = __builtin_amdgcn_mfma_f32_16x16x32_bf16(a1f, bfrag, acc1, 0, 0, 0);
            }
            float* part = smem;   // 8 * 512
#pragma unroll
            for (int r = 0; r < 4; ++r) {
                part[w*512 + (kq*4 + r)*16 + fr] = acc0[r];
                part[w*512 + 256 + (kq*4 + r)*16 + fr] = acc1[r];
            }
            __syncthreads();
            float rs = 0.0f;
#pragma unroll
            for (int w2 = 0; w2 < 8; ++w2) rs += part[w2*512 + tid];
            const float other = __shfl_xor(rs, 8);
            const int coli = tid & 15;
            const int m = ((tid >> 8) << 4) | ((tid >> 4) & 15);
            float gval = 0.0f;
            if (coli < 8) {
                const int c = c0 + coli;
                const float va = rs + p.bs2[c];
                const float vg = other + p.bs2[2048 + c];
                gval = va * sigf(vg);
                p.sg[m*2048 + c] = gval;
            }
            float s1 = gval, s2v = gval*gval;
            s1 += __shfl_xor(s1, 1); s2v += __shfl_xor(s2v, 1);
            s1 += __shfl_xor(s1, 2); s2v += __shfl_xor(s2v, 2);
            s1 += __shfl_xor(s1, 4); s2v += __shfl_xor(s2v, 4);
            if (coli == 0) {
                atomicAdd(&p.stats[m*2],     s1);
                atomicAdd(&p.stats[m*2 + 1], s2v);
            }
        }
        grid.sync();
        // ================= Phase C: LN + trace + NLM =================
        {
            const int n0 = bid * 8;
            float* tr  = smem;            // 256*12 = 3072
            float* pk  = smem + 3072;     // 16*520 = 8320
            float* h2s = smem + 11392;    // 512
            if (tid < 256) {
                const int bb = tid >> 3, nl0 = tid & 7;
                const int n = n0 + nl0;
                float* trow = &tr[tid * 12];
#pragma unroll
                for (int m = 0; m < 9; ++m) {
                    const int slot = (u + 1 + m) % 10;
                    trow[m] = p.trace[(bb*10 + slot)*2048 + n];
                }
                const float mean = p.stats[bb*2] * (1.0f/2048.0f);
                const float var  = p.stats[bb*2+1] * (1.0f/2048.0f) - mean*mean;
                const float rstd = rsqrtf(var + 1e-5f);
                const float v9 = (p.sg[bb*2048 + n] - mean) * rstd * p.ln_g[n] + p.ln_b[n];
                trow[9] = v9;
                p.trace[(bb*10 + (u % 10))*2048 + n] = v9;
            }
            const int nl = tid & 7, hg = tid >> 3;   // hg 0..63
            float w1a[10], w1g[10], b1a, b1g, w2v0, w2v1;
            {
                const unsigned short* pa = p.W1t + (((size_t)bid*128 + hg)*8 + nl)*16;
                const uint4 qa = *(const uint4*)pa;
                const uint4 qb = *(const uint4*)(pa + 8);
                w1a[0] = BLO(qa.x); w1a[1] = BHI(qa.x); w1a[2] = BLO(qa.y); w1a[3] = BHI(qa.y);
                w1a[4] = BLO(qa.z); w1a[5] = BHI(qa.z); w1a[6] = BLO(qa.w); w1a[7] = BHI(qa.w);
                w1a[8] = BLO(qb.x); w1a[9] = BHI(qb.x); b1a = BLO(qb.y);
                const unsigned short* pg = p.W1t + (((size_t)bid*128 + 64 + hg)*8 + nl)*16;
                const uint4 ra = *(const uint4*)pg;
                const uint4 rb = *(const uint4*)(pg + 8);
                w1g[0] = BLO(ra.x); w1g[1] = BHI(ra.x); w1g[2] = BLO(ra.y); w1g[3] = BHI(ra.y);
                w1g[4] = BLO(ra.z); w1g[5] = BHI(ra.z); w1g[6] = BLO(ra.w); w1g[7] = BHI(ra.w);
                w1g[8] = BLO(rb.x); w1g[9] = BHI(rb.x); b1g = BLO(rb.y);
                const unsigned int q2 = *(const unsigned int*)(p.W2t + (((size_t)bid*64 + hg)*8 + nl)*2);
                w2v0 = BLO(q2); w2v1 = BHI(q2);
            }
            __syncthreads();
            float a0[32], a1[32];
#pragma unroll
            for (int bb = 0; bb < 32; ++bb) {
                const float* trow = &tr[(bb*8 + nl)*12];
                const float4 t0 = *(const float4*)trow;
                const float4 t1 = *(const float4*)(trow + 4);
                const float2 t2 = *(const float2*)(trow + 8);
                const float t[10] = {t0.x,t0.y,t0.z,t0.w,t1.x,t1.y,t1.z,t1.w,t2.x,t2.y};
                float ha = b1a, hgv = b1g;
#pragma unroll
                for (int mm = 0; mm < 10; ++mm) {
                    ha  = fmaf(t[mm], w1a[mm], ha);
                    hgv = fmaf(t[mm], w1g[mm], hgv);
                }
                const float g0 = ha * sigf(hgv);
                a0[bb] = g0 * w2v0;
                a1[bb] = g0 * w2v1;
            }
            float rs = 0.0f;
#pragma unroll
            for (int pass = 0; pass < 4; ++pass) {
                __syncthreads();
                if ((hg >> 4) == pass) {
                    const int hgm = hg & 15;
#pragma unroll
                    for (int bb = 0; bb < 32; ++bb) {
                        float2 wv = { a0[bb], a1[bb] };
                        *(float2*)&pk[hgm*520 + bb*16 + nl*2] = wv;
                    }
                }
                __syncthreads();
                for (int hgm = 0; hgm < 16; ++hgm) rs += pk[hgm*520 + tid];
            }
            rs += p.b2[(n0 + ((tid >> 1) & 7))*2 + (tid & 1)];
            h2s[tid] = rs;
            __syncthreads();
            if (tid < 256) {
                const int bb = tid >> 3, nlx = tid & 7;
                const float a = h2s[bb*16 + nlx*2];
                const float gg = h2s[bb*16 + nlx*2 + 1];
                const float actv = a * sigf(gg);
                p.act[bb*2048 + n0 + nlx] = actv;
                p.Ab[bb*2560 + 512 + n0 + nlx] = bfr(actv);
            }
        }
        grid.sync();
    }
    // ================= Tail: final o-update + outputs (block 0) =================
    if (bid == 0) {
        float* sl = smem;
        for (int idx = tid; idx < 2048; idx += 512) {
            const int b = idx >> 6, j = idx & 63;
            const float ro = decf(p.dec_o[j]);
            const float po = p.act[b*2048 + p.iol[j]] * p.act[b*2048 + p.ior[j]];
            const float ao = fmaf(ro, p.aoB[2048 + b*64 + j], po);
            const float bo = fmaf(ro, p.boB[2048 + b*64 + j], 1.0f);
            const float sv = ao * rsqrtf(bo);
            sl[idx] = sv;
            p.out[96 + idx] = sv;
        }
        __syncthreads();
        if (tid < 32) {
            float pr = p.bout[0];
            for (int j = 0; j < 64; ++j) pr = fmaf(sl[tid*64 + j], p.Wout[j], pr);
            p.out[tid] = sigf(pr);
        } else if (tid < 96) {
            p.out[32 + (tid - 32)] = ((tid - 32) & 1) ? 1.0f : 0.0f;
        }
    }
}

// ---------------------------------------------------------------------------
extern "C" void kernel_launch(void* const* d_in, const int* in_sizes, int n_in,
                              void* d_out, int out_size, void* d_ws, size_t ws_size,
                              hipStream_t stream)
{
    (void)in_sizes; (void)n_in; (void)out_size;
    const int*   tok   = (const int*)  d_in[0];
    const float* emb   = (const float*)d_in[1];
    const float* st_tr = (const float*)d_in[2];
    const float* st_ac = (const float*)d_in[3];
    const float* dec_a = (const float*)d_in[4];
    const float* dec_o = (const float*)d_in[5];
    const int*   ial   = (const int*)  d_in[6];
    const int*   iar   = (const int*)  d_in[7];
    const int*   iol   = (const int*)  d_in[8];
    const int*   ior   = (const int*)  d_in[9];
    const float* Wq    = (const float*)d_in[10];
    const float* bq    = (const float*)d_in[11];
    const float* Win   = (const float*)d_in[12];
    const float* b_in  = (const float*)d_in[13];
    const float* Wao   = (const float*)d_in[14];
    const float* bao   = (const float*)d_in[15];
    const float* Wsyn  = (const float*)d_in[16];
    const float* bsyn  = (const float*)d_in[17];
    const float* ln_g  = (const float*)d_in[18];
    const float* ln_b  = (const float*)d_in[19];
    const float* W1    = (const float*)d_in[20];
    const float* b1    = (const float*)d_in[21];
    const float* W2    = (const float*)d_in[22];
    const float* b2    = (const float*)d_in[23];
    const float* Wout  = (const float*)d_in[24];
    const float* bout  = (const float*)d_in[25];
    float* out = (float*)d_out;
    char* wsb = (char*)d_ws;
    if (ws_size < (size_t)66814208) return;
    unsigned short* khb  = (unsigned short*)(wsb + 0);          // 16 MB
    unsigned short* vhb  = (unsigned short*)(wsb + 16777216);   // 16 MB
    unsigned short* Wall = (unsigned short*)(wsb + 33554432);   // 20 MB (4096x2560)
    unsigned short* W1t  = (unsigned short*)(wsb + 54525952);   // 8 MB
    unsigned short* W2t  = (unsigned short*)(wsb + 62914560);   // 512 KB
    float* trace = (float*)(wsb + 63438848);                    // 2.5 MB
    float* actb  = (float*)(wsb + 66060288);                    // 256 KB
    float* sg    = (float*)(wsb + 66322432);                    // 256 KB
    unsigned short* Ab = (unsigned short*)(wsb + 66584576);     // 160 KB (32x2560 bf16)
    float* aaB   = (float*)(wsb + 66748416);
    float* baB   = (float*)(wsb + 66756608);
    float* aoB   = (float*)(wsb + 66764800);
    float* boB   = (float*)(wsb + 66781184);
    float* bs2   = (float*)(wsb + 66797568);
    float* stats = (float*)(wsb + 66813952);

    k0_init<<<dim3(2841), dim3(256), 0, stream>>>(st_tr, st_ac, iol, ior,
        trace, actb, Ab, aaB, baB, aoB, boB, stats);
    s1_kv_mfma<<<dim3(1024), dim3(256), 0, stream>>>(tok, emb, Win, b_in, khb, vhb);
    s2_wfused<<<dim3(512), dim3(256), 0, stream>>>(Wsyn, Wao, Wall);
    s3_bias<<<dim3(16), dim3(256), 0, stream>>>(Wsyn, bao, bsyn, bs2);
    s4_convsyn<<<dim3(8192), dim3(256), 0, stream>>>(Wsyn, Wall);
    s5_convnlm<<<dim3(1024), dim3(256), 0, stream>>>(W1, b1, W2, W1t, W2t);

    TickParams tp;
    tp.act = actb; tp.dec_a = dec_a; tp.dec_o = dec_o;
    tp.ial = ial; tp.iar = iar; tp.iol = iol; tp.ior = ior;
    tp.Wq = Wq; tp.bq = bq; tp.Win = Win; tp.b_in = b_in;
    tp.khb = khb; tp.vhb = vhb;
    tp.aaB = aaB; tp.baB = baB; tp.aoB = aoB; tp.boB = boB;
    tp.Ab = Ab; tp.Wall = Wall; tp.bs2 = bs2;
    tp.sg = sg; tp.stats = stats; tp.ln_g = ln_g; tp.ln_b = ln_b;
    tp.W1t = W1t; tp.W2t = W2t; tp.b2 = b2;
    tp.trace = trace; tp.Wout = Wout; tp.bout = bout; tp.out = out;
    void* kargs[] = { (void*)&tp };
    hipLaunchCooperativeKernel(reinterpret_cast<void*>(ktick),
                               dim3(256), dim3(512), kargs, 0, stream);
}

// Round 5
// 1258.729 us; speedup vs baseline: 2.1329x; 2.1329x over previous
//
#include <hip/hip_runtime.h>
#include <math.h>

// Sizes: B=32 S=512 V=32000 D_IN=512 D_MODEL=2048 HEADS=8 HD=64
//        N_OUT=64 N_ACT=32 M=10 MH=64 T=20

typedef __attribute__((ext_vector_type(8))) short short8v;
typedef __attribute__((ext_vector_type(4))) float f32x4;

__device__ __forceinline__ float sigf(float x) { return 1.0f / (1.0f + __expf(-x)); }
__device__ __forceinline__ float decf(float d) { return __expf(-fminf(fmaxf(d, 0.0f), 15.0f)); }
__device__ __forceinline__ unsigned short bfr(float x) {
    unsigned int u = __float_as_uint(x);
    u += 0x7FFFu + ((u >> 16) & 1u);
    return (unsigned short)(u >> 16);
}
__device__ __forceinline__ float bff(unsigned short u) {
    return __uint_as_float(((unsigned int)u) << 16);
}
__device__ __forceinline__ unsigned int bf2(float lo, float hi) {
    unsigned int ul = __float_as_uint(lo); ul += 0x7FFFu + ((ul >> 16) & 1u);
    unsigned int uh = __float_as_uint(hi); uh += 0x7FFFu + ((uh >> 16) & 1u);
    return (ul >> 16) | (uh & 0xFFFF0000u);
}
#define BLO(u) __uint_as_float((u) << 16)
#define BHI(u) __uint_as_float((u) & 0xFFFF0000u)
__device__ __forceinline__ int SWZ(int byteoff) {
    return byteoff ^ (((byteoff >> 7) & 7) << 4);
}

// ---------------------------------------------------------------------------
// K0: init trace, act (+Ab act half), aa/ba, ao/bo, stats
// ---------------------------------------------------------------------------
__global__ __launch_bounds__(256) void k0_init(
    const float* __restrict__ st_tr, const float* __restrict__ st_ac,
    const int* __restrict__ iol, const int* __restrict__ ior,
    float* __restrict__ trace, float* __restrict__ act,
    unsigned short* __restrict__ Ab,
    float* __restrict__ aaB, float* __restrict__ baB,
    float* __restrict__ aoB, float* __restrict__ boB, float* __restrict__ stats)
{
    const int i = blockIdx.x * 256 + threadIdx.x;
    if (i < 655360) {
        const int n = i & 2047;
        const int m = (i >> 11) % 10;
        trace[i] = st_tr[n * 10 + m];
    } else if (i < 720896) {
        const int j = i - 655360;
        const int n = j & 2047, b = j >> 11;
        const float v = st_ac[n];
        act[j] = v;
        Ab[b * 2560 + 512 + n] = bfr(v);
    } else if (i < 721920) {
        aaB[i - 720896] = 0.0f;
    } else if (i < 722944) {
        baB[i - 721920] = 0.0f;
    } else if (i < 724992) {
        const int j = i - 722944;
        const int k = j & 63;
        aoB[j] = st_ac[iol[k]] * st_ac[ior[k]];
    } else if (i < 727040) {
        boB[i - 724992] = 1.0f;
    } else if (i < 727104) {
        stats[i - 727040] = 0.0f;
    }
}

// ---------------------------------------------------------------------------
// S1: MFMA bf16 GEMM: C(16384x1024) = gather(emb,tok) @ WinKV^T -> khb/vhb
// grid swizzled: cb = bid>>7 so one rb's 8 c-blocks share an XCD L2
// ---------------------------------------------------------------------------
__global__ __launch_bounds__(256) void s1_kv_mfma(
    const int* __restrict__ tok, const float* __restrict__ emb,
    const float* __restrict__ Win, const float* __restrict__ b_in,
    unsigned short* __restrict__ khb, unsigned short* __restrict__ vhb)
{
    __shared__ alignas(16) unsigned short Al[128 * 64];
    __shared__ alignas(16) unsigned short Bl[128 * 64];
    const int tid = threadIdx.x;
    const int cb = blockIdx.x >> 7;
    const int rb = blockIdx.x & 127;
    const int r0 = rb * 128, c0 = cb * 128;
    int tokrow[8];
#pragma unroll
    for (int j = 0; j < 8; ++j) tokrow[j] = tok[r0 + ((tid + 256 * j) >> 4)];

    const int wid = tid >> 6, lane = tid & 63;
    const int wm = (wid >> 1) * 64, wn = (wid & 1) * 64;
    const int fr = lane & 15;
    const int fkb = (lane >> 4) * 16;
    f32x4 acc[4][4];
#pragma unroll
    for (int i = 0; i < 4; ++i)
#pragma unroll
        for (int j = 0; j < 4; ++j)
#pragma unroll
            for (int e = 0; e < 4; ++e) acc[i][j][e] = 0.0f;

    for (int kt = 0; kt < 512; kt += 64) {
        float4 av[8], bv[8];
#pragma unroll
        for (int j = 0; j < 8; ++j) {
            const int flat = tid + 256 * j;
            const int row = flat >> 4, kq4 = flat & 15;
            av[j] = *(const float4*)(emb + (size_t)tokrow[j] * 512 + kt + kq4 * 4);
            bv[j] = *(const float4*)(Win + (size_t)(512 + c0 + row) * 512 + kt + kq4 * 4);
        }
        __syncthreads();
#pragma unroll
        for (int j = 0; j < 8; ++j) {
            const int flat = tid + 256 * j;
            const int row = flat >> 4, kq4 = flat & 15;
            const int boff = row * 128 + kq4 * 8;
            uint2 pa = { bf2(av[j].x, av[j].y), bf2(av[j].z, av[j].w) };
            uint2 pb = { bf2(bv[j].x, bv[j].y), bf2(bv[j].z, bv[j].w) };
            *(uint2*)((char*)Al + SWZ(boff)) = pa;
            *(uint2*)((char*)Bl + SWZ(boff)) = pb;
        }
        __syncthreads();
#pragma unroll
        for (int ks = 0; ks < 2; ++ks) {
            short8v af[4], bfv[4];
#pragma unroll
            for (int i = 0; i < 4; ++i)
                af[i] = *(const short8v*)((const char*)Al + SWZ((wm + i * 16 + fr) * 128 + ks * 64 + fkb));
#pragma unroll
            for (int j = 0; j < 4; ++j)
                bfv[j] = *(const short8v*)((const char*)Bl + SWZ((wn + j * 16 + fr) * 128 + ks * 64 + fkb));
#pragma unroll
            for (int i = 0; i < 4; ++i)
#pragma unroll
                for (int j = 0; j < 4; ++j)
                    acc[i][j] = __builtin_amdgcn_mfma_f32_16x16x32_bf16(af[i], bfv[j], acc[i][j], 0, 0, 0);
        }
    }
    unsigned short* outbase = (c0 < 512) ? khb : vhb;
    const int ccol = (c0 < 512) ? c0 : (c0 - 512);
#pragma unroll
    for (int j = 0; j < 4; ++j) {
        const int n = wn + j * 16 + fr;
        const float bias = b_in[512 + c0 + n];
#pragma unroll
        for (int i = 0; i < 4; ++i) {
            const int mbase = wm + i * 16 + (lane >> 4) * 4;
#pragma unroll
            for (int rr = 0; rr < 4; ++rr) {
                const int gr = r0 + mbase + rr;
                outbase[(size_t)gr * 512 + ccol + n] = bfr(acc[i][j][rr] + bias);
            }
        }
    }
}

// ---------------------------------------------------------------------------
// S2: Wall[c][0..511] = bf16( Wsyn[c][0:512] @ Wattn_o )  (stride 2560)
// ---------------------------------------------------------------------------
__global__ __launch_bounds__(256) void s2_wfused(
    const float* __restrict__ Wsyn, const float* __restrict__ Wao,
    unsigned short* __restrict__ Wall)
{
    __shared__ float As[16][68];
    __shared__ float Bs[16][68];
    const int tid = threadIdx.x;
    const int cb = blockIdx.x & 7;
    const int rb = blockIdx.x >> 3;
    const int r0 = rb * 64, c0 = cb * 64;
    const int ra = tid >> 2, kq = tid & 3;
    const int bk = tid >> 4, bq = tid & 15;
    const int tx = tid & 15, ty = tid >> 4;
    float acc[4][4];
#pragma unroll
    for (int i = 0; i < 4; ++i)
#pragma unroll
        for (int j = 0; j < 4; ++j) acc[i][j] = 0.0f;

    for (int kt = 0; kt < 512; kt += 16) {
        const float4 av = *(const float4*)(Wsyn + (size_t)(r0 + ra) * 2560 + kt + kq * 4);
        const float4 bv = *(const float4*)(Wao + (size_t)(kt + bk) * 512 + c0 + bq * 4);
        __syncthreads();
        As[kq*4+0][ra] = av.x; As[kq*4+1][ra] = av.y; As[kq*4+2][ra] = av.z; As[kq*4+3][ra] = av.w;
        *(float4*)&Bs[bk][bq*4] = bv;
        __syncthreads();
#pragma unroll
        for (int kk = 0; kk < 16; ++kk) {
            const float4 a4 = *(const float4*)&As[kk][ty*4];
            const float4 b4 = *(const float4*)&Bs[kk][tx*4];
            const float a[4] = {a4.x, a4.y, a4.z, a4.w};
            const float b[4] = {b4.x, b4.y, b4.z, b4.w};
#pragma unroll
            for (int i = 0; i < 4; ++i)
#pragma unroll
                for (int j = 0; j < 4; ++j) acc[i][j] = fmaf(a[i], b[j], acc[i][j]);
        }
    }
#pragma unroll
    for (int i = 0; i < 4; ++i) {
        const int gr = r0 + ty*4 + i;
        uint2 o = { bf2(acc[i][0], acc[i][1]), bf2(acc[i][2], acc[i][3]) };
        *(uint2*)(Wall + (size_t)gr*2560 + c0 + tx*4) = o;
    }
}

// ---------------------------------------------------------------------------
// S3: bsyn2[c] = bsyn[c] + sum_k battn_o[k] * Wsyn[c][k]
// ---------------------------------------------------------------------------
__global__ __launch_bounds__(256) void s3_bias(
    const float* __restrict__ Wsyn, const float* __restrict__ battn,
    const float* __restrict__ bsyn, float* __restrict__ bsyn2)
{
    const int c = blockIdx.x * 256 + threadIdx.x;
    float s = bsyn[c];
    const float4* wr = (const float4*)(Wsyn + (size_t)c * 2560);
#pragma unroll 4
    for (int k4 = 0; k4 < 128; ++k4) {
        const float4 w = wr[k4];
        const float4 bb = *(const float4*)(battn + k4*4);
        s += w.x*bb.x + w.y*bb.y + w.z*bb.z + w.w*bb.w;
    }
    bsyn2[c] = s;
}

// ---------------------------------------------------------------------------
// S4: Wall[c][512..2559] = bf16(Wsyn[:, 512:2560])
// ---------------------------------------------------------------------------
__global__ __launch_bounds__(256) void s4_convsyn(
    const float* __restrict__ Wsyn, unsigned short* __restrict__ Wall)
{
    const int idx = blockIdx.x * 256 + threadIdx.x;
    const int row = (idx * 4) >> 11, col = (idx * 4) & 2047;
    const float4 v = *(const float4*)(Wsyn + (size_t)row * 2560 + 512 + col);
    uint2 o = { bf2(v.x, v.y), bf2(v.z, v.w) };
    *(uint2*)(Wall + (size_t)row * 2560 + 512 + col) = o;
}

// ---------------------------------------------------------------------------
// S5: NLM weight re-layout: W1t[(n>>2)*128+hh][n&3][16], W2t[(n>>2)*64+hq][n&3][2]
// ---------------------------------------------------------------------------
__global__ __launch_bounds__(256) void s5_convnlm(
    const float* __restrict__ W1, const float* __restrict__ b1,
    const float* __restrict__ W2,
    unsigned short* __restrict__ W1t, unsigned short* __restrict__ W2t)
{
    const int t = blockIdx.x * 256 + threadIdx.x;   // 0..262143
    const int n = t & 2047, hh = t >> 11;
    unsigned short tmp[16];
#pragma unroll
    for (int m = 0; m < 10; ++m) tmp[m] = bfr(W1[(size_t)(m * 128 + hh) * 2048 + n]);
    tmp[10] = bfr(b1[n * 128 + hh]);
    tmp[11] = 0; tmp[12] = 0; tmp[13] = 0; tmp[14] = 0; tmp[15] = 0;
    uint4 lo = { (unsigned)tmp[0] | ((unsigned)tmp[1] << 16), (unsigned)tmp[2] | ((unsigned)tmp[3] << 16),
                 (unsigned)tmp[4] | ((unsigned)tmp[5] << 16), (unsigned)tmp[6] | ((unsigned)tmp[7] << 16) };
    uint4 hi = { (unsigned)tmp[8] | ((unsigned)tmp[9] << 16), (unsigned)tmp[10] | ((unsigned)tmp[11] << 16),
                 (unsigned)tmp[12] | ((unsigned)tmp[13] << 16), (unsigned)tmp[14] | ((unsigned)tmp[15] << 16) };
    const size_t o1 = ((size_t)((n >> 2) * 128 + hh) * 4 + (n & 3)) * 16;
    *(uint4*)(W1t + o1) = lo;
    *(uint4*)(W1t + o1 + 8) = hi;
    if (hh < 64) {
        const unsigned short a = bfr(W2[(size_t)(hh * 2 + 0) * 2048 + n]);
        const unsigned short g = bfr(W2[(size_t)(hh * 2 + 1) * 2048 + n]);
        *(unsigned int*)(W2t + ((size_t)((n >> 2) * 64 + hh) * 4 + (n & 3)) * 2) =
            (unsigned)a | ((unsigned)g << 16);
    }
}

// ---------------------------------------------------------------------------
// S6a: M[h][d][j] = Wpq[h*64+d] . Wq[:,j] -> bf16 Mb; qc0[h*64+d] = bpq + Wpq.bq
// ---------------------------------------------------------------------------
__global__ __launch_bounds__(256) void s6a_mproj(
    const float* __restrict__ Win, const float* __restrict__ b_in,
    const float* __restrict__ Wq, const float* __restrict__ bq,
    unsigned short* __restrict__ Mb, float* __restrict__ qc0)
{
    __shared__ float wq[16384];  // 512 x 32
    __shared__ float bql[512];
    const int tid = threadIdx.x;
    const int h = blockIdx.x;
    for (int i = tid; i < 4096; i += 256) ((float4*)wq)[i] = ((const float4*)Wq)[i];
    for (int i = tid; i < 128; i += 256) ((float4*)bql)[i] = ((const float4*)bq)[i];
    __syncthreads();
#pragma unroll
    for (int i = 0; i < 8; ++i) {
        const int p = tid + 256 * i;
        const int d = p >> 5, j = p & 31;
        const float* row = Win + (size_t)(h * 64 + d) * 512;
        float s = 0.0f;
        for (int c = 0; c < 512; c += 4) {
            const float4 r4 = *(const float4*)(row + c);
            s += r4.x * wq[(c+0)*32 + j] + r4.y * wq[(c+1)*32 + j]
               + r4.z * wq[(c+2)*32 + j] + r4.w * wq[(c+3)*32 + j];
        }
        Mb[((size_t)h * 64 + d) * 32 + j] = bfr(s);
    }
    if (tid < 64) {
        const float* row = Win + (size_t)(h * 64 + tid) * 512;
        float s = b_in[h * 64 + tid];
        for (int c = 0; c < 512; c += 4) {
            const float4 r4 = *(const float4*)(row + c);
            const float4 b4 = *(const float4*)(bql + c);
            s += r4.x*b4.x + r4.y*b4.y + r4.z*b4.z + r4.w*b4.w;
        }
        qc0[h * 64 + tid] = s;
    }
}

// ---------------------------------------------------------------------------
// S6b: khM[b][h][s][j] = bf16( kh[r, h*64:..] . M[h][:,j] ); khc = kh . qc0
// grid 512 (32 rows each), 256 thr = (rl = tid>>3, h = tid&7)
// ---------------------------------------------------------------------------
#define MSTR 2096
__global__ __launch_bounds__(256) void s6b_khm(
    const unsigned short* __restrict__ khb, const unsigned short* __restrict__ Mb,
    const float* __restrict__ qc0,
    unsigned short* __restrict__ khM, float* __restrict__ khc)
{
    __shared__ alignas(16) unsigned short ml[8 * MSTR];
    __shared__ float ql[8 * 68];
    const int tid = threadIdx.x;
    for (int i = tid; i < 2048; i += 256) {
        const int h = i >> 8, rem = i & 255;
        *(uint4*)&ml[h * MSTR + rem * 8] = ((const uint4*)Mb)[i];
    }
    for (int i = tid; i < 512; i += 256) ql[(i >> 6) * 68 + (i & 63)] = qc0[i];
    __syncthreads();
    const int rl = tid >> 3, h = tid & 7;
    const int r = blockIdx.x * 32 + rl;
    uint4 kr[8];
#pragma unroll
    for (int i = 0; i < 8; ++i)
        kr[i] = *(const uint4*)(khb + (size_t)r * 512 + h * 64 + i * 8);
    float acc[32];
#pragma unroll
    for (int j = 0; j < 32; ++j) acc[j] = 0.0f;
    float kc = 0.0f;
    const unsigned short* mrow = &ml[h * MSTR];
    const float* qrow = &ql[h * 68];
#pragma unroll
    for (int dq = 0; dq < 8; ++dq) {
        float k8[8];
        k8[0] = BLO(kr[dq].x); k8[1] = BHI(kr[dq].x);
        k8[2] = BLO(kr[dq].y); k8[3] = BHI(kr[dq].y);
        k8[4] = BLO(kr[dq].z); k8[5] = BHI(kr[dq].z);
        k8[6] = BLO(kr[dq].w); k8[7] = BHI(kr[dq].w);
#pragma unroll
        for (int dd = 0; dd < 8; ++dd) {
            const int d = dq * 8 + dd;
            const float kf = k8[dd];
            kc = fmaf(kf, qrow[d], kc);
            const uint4 m0 = *(const uint4*)&mrow[d * 32];
            const uint4 m1 = *(const uint4*)&mrow[d * 32 + 8];
            const uint4 m2 = *(const uint4*)&mrow[d * 32 + 16];
            const uint4 m3 = *(const uint4*)&mrow[d * 32 + 24];
            acc[0]  = fmaf(kf, BLO(m0.x), acc[0]);  acc[1]  = fmaf(kf, BHI(m0.x), acc[1]);
            acc[2]  = fmaf(kf, BLO(m0.y), acc[2]);  acc[3]  = fmaf(kf, BHI(m0.y), acc[3]);
            acc[4]  = fmaf(kf, BLO(m0.z), acc[4]);  acc[5]  = fmaf(kf, BHI(m0.z), acc[5]);
            acc[6]  = fmaf(kf, BLO(m0.w), acc[6]);  acc[7]  = fmaf(kf, BHI(m0.w), acc[7]);
            acc[8]  = fmaf(kf, BLO(m1.x), acc[8]);  acc[9]  = fmaf(kf, BHI(m1.x), acc[9]);
            acc[10] = fmaf(kf, BLO(m1.y), acc[10]); acc[11] = fmaf(kf, BHI(m1.y), acc[11]);
            acc[12] = fmaf(kf, BLO(m1.z), acc[12]); acc[13] = fmaf(kf, BHI(m1.z), acc[13]);
            acc[14] = fmaf(kf, BLO(m1.w), acc[14]); acc[15] = fmaf(kf, BHI(m1.w), acc[15]);
            acc[16] = fmaf(kf, BLO(m2.x), acc[16]); acc[17] = fmaf(kf, BHI(m2.x), acc[17]);
            acc[18] = fmaf(kf, BLO(m2.y), acc[18]); acc[19] = fmaf(kf, BHI(m2.y), acc[19]);
            acc[20] = fmaf(kf, BLO(m2.z), acc[20]); acc[21] = fmaf(kf, BHI(m2.z), acc[21]);
            acc[22] = fmaf(kf, BLO(m2.w), acc[22]); acc[23] = fmaf(kf, BHI(m2.w), acc[23]);
            acc[24] = fmaf(kf, BLO(m3.x), acc[24]); acc[25] = fmaf(kf, BHI(m3.x), acc[25]);
            acc[26] = fmaf(kf, BLO(m3.y), acc[26]); acc[27] = fmaf(kf, BHI(m3.y), acc[27]);
            acc[28] = fmaf(kf, BLO(m3.z), acc[28]); acc[29] = fmaf(kf, BHI(m3.z), acc[29]);
            acc[30] = fmaf(kf, BLO(m3.w), acc[30]); acc[31] = fmaf(kf, BHI(m3.w), acc[31]);
        }
    }
    const int b = r >> 9, s = r & 511;
    unsigned short* dst = khM + (((size_t)b * 8 + h) * 512 + s) * 32;
    uint4 o0 = { bf2(acc[0],acc[1]), bf2(acc[2],acc[3]), bf2(acc[4],acc[5]), bf2(acc[6],acc[7]) };
    uint4 o1 = { bf2(acc[8],acc[9]), bf2(acc[10],acc[11]), bf2(acc[12],acc[13]), bf2(acc[14],acc[15]) };
    uint4 o2 = { bf2(acc[16],acc[17]), bf2(acc[18],acc[19]), bf2(acc[20],acc[21]), bf2(acc[22],acc[23]) };
    uint4 o3 = { bf2(acc[24],acc[25]), bf2(acc[26],acc[27]), bf2(acc[28],acc[29]), bf2(acc[30],acc[31]) };
    ((uint4*)dst)[0] = o0; ((uint4*)dst)[1] = o1; ((uint4*)dst)[2] = o2; ((uint4*)dst)[3] = o3;
    khc[((size_t)b * 8 + h) * 512 + s] = kc;
}

// ---------------------------------------------------------------------------
// K1: per (b,h), 512 thr: EMA; score = 0.125*(khM.sync + khc); shfl softmax;
// PV from preloaded vh regs -> Ab bf16
// ---------------------------------------------------------------------------
__global__ __launch_bounds__(512) void k1_attn(
    const float* __restrict__ act, const float* __restrict__ decay_a,
    const float* __restrict__ decay_o, const int* __restrict__ ial,
    const int* __restrict__ iar, const int* __restrict__ iol,
    const int* __restrict__ ior,
    const unsigned short* __restrict__ khM, const float* __restrict__ khc,
    const unsigned short* __restrict__ vhb, float* __restrict__ aaB,
    float* __restrict__ baB, float* __restrict__ aoB, float* __restrict__ boB,
    unsigned short* __restrict__ Ab, float* __restrict__ stats, const int u)
{
    __shared__ float sync_lds[32];
    __shared__ float sc[512];
    __shared__ float red[16];
    __shared__ float pvred[512];
    const int tid = threadIdx.x;
    const int b = blockIdx.x >> 3, h = blockIdx.x & 7;

    // preload khM row + khc + vh column (issued before EMA for latency overlap)
    const size_t mb = (((size_t)b * 8 + h) * 512 + tid) * 32;
    const uint4 km0 = *(const uint4*)(khM + mb);
    const uint4 km1 = *(const uint4*)(khM + mb + 8);
    const uint4 km2 = *(const uint4*)(khM + mb + 16);
    const uint4 km3 = *(const uint4*)(khM + mb + 24);
    const float kc = khc[((size_t)b * 8 + h) * 512 + tid];
    const int l = tid & 63, w = tid >> 6;
    const unsigned short* vb = vhb + ((size_t)(b * 512 + w * 64)) * 512 + h * 64 + l;
    unsigned short vraw[64];
#pragma unroll
    for (int si = 0; si < 64; ++si) vraw[si] = vb[(size_t)si * 512];

    if (tid < 32) {
        const int j = tid;
        const float ra = decf(decay_a[j]);
        const float pa = act[b*2048 + ial[j]] * act[b*2048 + iar[j]];
        const float aa = fmaf(ra, aaB[(u & 1)*1024 + b*32 + j], pa);
        const float ban = fmaf(ra, baB[(u & 1)*1024 + b*32 + j], 1.0f);
        if (h == 0) { aaB[((u+1)&1)*1024 + b*32 + j] = aa; baB[((u+1)&1)*1024 + b*32 + j] = ban; }
        sync_lds[j] = aa * rsqrtf(ban);
    } else if (tid >= 64 && tid < 128) {
        if (u > 0) {
            const int j = tid - 64;
            const float ro = decf(decay_o[j]);
            const float po = act[b*2048 + iol[j]] * act[b*2048 + ior[j]];
            const float ao = fmaf(ro, aoB[((u-1)&1)*2048 + b*64 + j], po);
            const float bo = fmaf(ro, boB[((u-1)&1)*2048 + b*64 + j], 1.0f);
            if (h == 0) { aoB[(u&1)*2048 + b*64 + j] = ao; boB[(u&1)*2048 + b*64 + j] = bo; }
        }
    } else if (tid >= 128 && tid < 192) {
        if (u > 0 && blockIdx.x == 0) stats[tid - 128] = 0.0f;
    }
    __syncthreads();
    // score
    float sv = kc;
    {
        const float* sy = sync_lds;
        sv = fmaf(BLO(km0.x), sy[0], sv);  sv = fmaf(BHI(km0.x), sy[1], sv);
        sv = fmaf(BLO(km0.y), sy[2], sv);  sv = fmaf(BHI(km0.y), sy[3], sv);
        sv = fmaf(BLO(km0.z), sy[4], sv);  sv = fmaf(BHI(km0.z), sy[5], sv);
        sv = fmaf(BLO(km0.w), sy[6], sv);  sv = fmaf(BHI(km0.w), sy[7], sv);
        sv = fmaf(BLO(km1.x), sy[8], sv);  sv = fmaf(BHI(km1.x), sy[9], sv);
        sv = fmaf(BLO(km1.y), sy[10], sv); sv = fmaf(BHI(km1.y), sy[11], sv);
        sv = fmaf(BLO(km1.z), sy[12], sv); sv = fmaf(BHI(km1.z), sy[13], sv);
        sv = fmaf(BLO(km1.w), sy[14], sv); sv = fmaf(BHI(km1.w), sy[15], sv);
        sv = fmaf(BLO(km2.x), sy[16], sv); sv = fmaf(BHI(km2.x), sy[17], sv);
        sv = fmaf(BLO(km2.y), sy[18], sv); sv = fmaf(BHI(km2.y), sy[19], sv);
        sv = fmaf(BLO(km2.z), sy[20], sv); sv = fmaf(BHI(km2.z), sy[21], sv);
        sv = fmaf(BLO(km2.w), sy[22], sv); sv = fmaf(BHI(km2.w), sy[23], sv);
        sv = fmaf(BLO(km3.x), sy[24], sv); sv = fmaf(BHI(km3.x), sy[25], sv);
        sv = fmaf(BLO(km3.y), sy[26], sv); sv = fmaf(BHI(km3.y), sy[27], sv);
        sv = fmaf(BLO(km3.z), sy[28], sv); sv = fmaf(BHI(km3.z), sy[29], sv);
        sv = fmaf(BLO(km3.w), sy[30], sv); sv = fmaf(BHI(km3.w), sy[31], sv);
    }
    const float v = sv * 0.125f;
    // softmax over 512
    const int wid = tid >> 6;
    float m = v;
#pragma unroll
    for (int off = 32; off > 0; off >>= 1) m = fmaxf(m, __shfl_xor(m, off));
    if ((tid & 63) == 0) red[wid] = m;
    __syncthreads();
    float mx = red[0];
#pragma unroll
    for (int j = 1; j < 8; ++j) mx = fmaxf(mx, red[j]);
    const float e = __expf(v - mx);
    sc[tid] = e;
    float s = e;
#pragma unroll
    for (int off = 32; off > 0; off >>= 1) s += __shfl_xor(s, off);
    if ((tid & 63) == 0) red[8 + wid] = s;
    __syncthreads();
    float tot = red[8];
#pragma unroll
    for (int j = 1; j < 8; ++j) tot += red[8 + j];
    const float inv = 1.0f / tot;
    // PV from preloaded regs
    {
        float a3 = 0.0f;
#pragma unroll
        for (int si = 0; si < 64; ++si)
            a3 = fmaf(sc[w*64 + si], bff(vraw[si]), a3);
        pvred[w*64 + l] = a3;
    }
    __syncthreads();
    if (tid < 64) {
        float a = 0.0f;
#pragma unroll
        for (int j = 0; j < 8; ++j) a += pvred[j*64 + tid];
        Ab[b*2560 + h*64 + tid] = bfr(a * inv);
    }
}

// ---------------------------------------------------------------------------
// K2b: synapse via MFMA: 256 blocks x 512 thr; block = 8 c-pairs; K split
// across 8 waves; LDS part-reduce; GLU -> sg; LN stats atomics
// ---------------------------------------------------------------------------
__global__ __launch_bounds__(512) void k2b_syn(
    const unsigned short* __restrict__ Ab, const unsigned short* __restrict__ Wall,
    const float* __restrict__ bsyn2, float* __restrict__ sg, float* __restrict__ stats)
{
    __shared__ float part[8 * 512];
    const int tid = threadIdx.x;
    const int c0 = blockIdx.x * 8;
    const int w = tid >> 6, lane = tid & 63, fr = lane & 15, kq = lane >> 4;
    const int col = (fr < 8) ? (c0 + fr) : (2048 + c0 + fr - 8);
    const unsigned short* wrow = Wall + (size_t)col * 2560 + w*320 + kq*8;
    const unsigned short* ar0 = Ab + (size_t)fr * 2560 + w*320 + kq*8;
    const unsigned short* ar1 = Ab + (size_t)(16 + fr) * 2560 + w*320 + kq*8;
    f32x4 acc0 = {0.f,0.f,0.f,0.f}, acc1 = {0.f,0.f,0.f,0.f};
#pragma unroll
    for (int kk = 0; kk < 10; ++kk) {
        const short8v bfrag = *(const short8v*)(wrow + kk*32);
        const short8v a0f = *(const short8v*)(ar0 + kk*32);
        const short8v a1f = *(const short8v*)(ar1 + kk*32);
        acc0 = __builtin_amdgcn_mfma_f32_16x16x32_bf16(a0f, bfrag, acc0, 0, 0, 0);
        acc1 = __builtin_amdgcn_mfma_f32_16x16x32_bf16(a1f, bfrag, acc1, 0, 0, 0);
    }
#pragma unroll
    for (int r = 0; r < 4; ++r) {
        part[w*512 + (kq*4 + r)*16 + fr] = acc0[r];
        part[w*512 + 256 + (kq*4 + r)*16 + fr] = acc1[r];
    }
    __syncthreads();
    float rs = 0.0f;
#pragma unroll
    for (int w2 = 0; w2 < 8; ++w2) rs += part[w2*512 + tid];
    const float other = __shfl_xor(rs, 8);
    const int coli = tid & 15;
    const int m = ((tid >> 8) << 4) | ((tid >> 4) & 15);
    float gval = 0.0f;
    if (coli < 8) {
        const int c = c0 + coli;
        const float va = rs + bsyn2[c];
        const float vg = other + bsyn2[2048 + c];
        gval = va * sigf(vg);
        sg[m*2048 + c] = gval;
    }
    float s1 = gval, s2v = gval*gval;
    s1 += __shfl_xor(s1, 1); s2v += __shfl_xor(s2v, 1);
    s1 += __shfl_xor(s1, 2); s2v += __shfl_xor(s2v, 2);
    s1 += __shfl_xor(s1, 4); s2v += __shfl_xor(s2v, 4);
    if (coli == 0) {
        atomicAdd(&stats[m*2],     s1);
        atomicAdd(&stats[m*2 + 1], s2v);
    }
}

// ---------------------------------------------------------------------------
// K3: LN + trace + per-neuron NLM -> act (+Ab). grid 512 (4 neurons), 256 thr
// ---------------------------------------------------------------------------
__global__ __launch_bounds__(256) void k3_nlm(
    const float* __restrict__ sg, const float* __restrict__ stats,
    const float* __restrict__ ln_g, const float* __restrict__ ln_b,
    const unsigned short* __restrict__ W1t, const unsigned short* __restrict__ W2t,
    const float* __restrict__ b2,
    float* __restrict__ trace, float* __restrict__ act,
    unsigned short* __restrict__ Ab, const int u)
{
    __shared__ float tr[128 * 12];
    __shared__ float pk[32 * 260];
    __shared__ float h2s[256];
    const int tid = threadIdx.x;
    const int n0 = blockIdx.x * 4;
    if (tid < 128) {
        const int bb = tid >> 2, nl0 = tid & 3;
        const int n = n0 + nl0;
        float* trow = &tr[tid * 12];
#pragma unroll
        for (int m = 0; m < 9; ++m) {
            const int slot = (u + 1 + m) % 10;
            trow[m] = trace[(bb*10 + slot)*2048 + n];
        }
        const float mean = stats[bb*2] * (1.0f/2048.0f);
        const float var  = stats[bb*2+1] * (1.0f/2048.0f) - mean*mean;
        const float rstd = rsqrtf(var + 1e-5f);
        const float v9 = (sg[bb*2048 + n] - mean) * rstd * ln_g[n] + ln_b[n];
        trow[9] = v9;
        trace[(bb*10 + (u % 10))*2048 + n] = v9;
    }
    const int nl = tid & 3, hg = tid >> 2;
    const int g = n0 >> 2;
    float w1a[10], w1g[10], b1a, b1g, w2v0, w2v1;
    {
        const unsigned short* pa = W1t + ((size_t)(g*128 + hg)*4 + nl)*16;
        const uint4 qa = *(const uint4*)pa;
        const uint4 qb = *(const uint4*)(pa + 8);
        w1a[0] = BLO(qa.x); w1a[1] = BHI(qa.x); w1a[2] = BLO(qa.y); w1a[3] = BHI(qa.y);
        w1a[4] = BLO(qa.z); w1a[5] = BHI(qa.z); w1a[6] = BLO(qa.w); w1a[7] = BHI(qa.w);
        w1a[8] = BLO(qb.x); w1a[9] = BHI(qb.x); b1a = BLO(qb.y);
        const unsigned short* pg = W1t + ((size_t)(g*128 + 64 + hg)*4 + nl)*16;
        const uint4 ra = *(const uint4*)pg;
        const uint4 rb = *(const uint4*)(pg + 8);
        w1g[0] = BLO(ra.x); w1g[1] = BHI(ra.x); w1g[2] = BLO(ra.y); w1g[3] = BHI(ra.y);
        w1g[4] = BLO(ra.z); w1g[5] = BHI(ra.z); w1g[6] = BLO(ra.w); w1g[7] = BHI(ra.w);
        w1g[8] = BLO(rb.x); w1g[9] = BHI(rb.x); b1g = BLO(rb.y);
        const unsigned int q2 = *(const unsigned int*)(W2t + ((size_t)(g*64 + hg)*4 + nl)*2);
        w2v0 = BLO(q2); w2v1 = BHI(q2);
    }
    __syncthreads();
    float a0[32], a1[32];
#pragma unroll
    for (int bb = 0; bb < 32; ++bb) {
        const float* trow = &tr[(bb*4 + nl)*12];
        const float4 t0 = *(const float4*)trow;
        const float4 t1 = *(const float4*)(trow + 4);
        const float2 t2 = *(const float2*)(trow + 8);
        const float t[10] = {t0.x,t0.y,t0.z,t0.w,t1.x,t1.y,t1.z,t1.w,t2.x,t2.y};
        float ha = b1a, hgv = b1g;
#pragma unroll
        for (int mm = 0; mm < 10; ++mm) {
            ha  = fmaf(t[mm], w1a[mm], ha);
            hgv = fmaf(t[mm], w1g[mm], hgv);
        }
        const float g0 = ha * sigf(hgv);
        a0[bb] = g0 * w2v0;
        a1[bb] = g0 * w2v1;
    }
    float rs = 0.0f;
#pragma unroll
    for (int pass = 0; pass < 2; ++pass) {
        __syncthreads();
        if ((hg >> 5) == pass) {
            const int hgm = hg & 31;
#pragma unroll
            for (int bb = 0; bb < 32; ++bb) {
                pk[hgm*260 + bb*8 + nl*2 + 0] = a0[bb];
                pk[hgm*260 + bb*8 + nl*2 + 1] = a1[bb];
            }
        }
        __syncthreads();
        for (int hgm = 0; hgm < 32; ++hgm) rs += pk[hgm*260 + tid];
    }
    const int onl = (tid >> 1) & 3, oo = tid & 1;
    rs += b2[(n0 + onl)*2 + oo];
    h2s[tid] = rs;
    __syncthreads();
    if (tid < 128) {
        const int bb = tid >> 2, nlx = tid & 3;
        const float h2a = h2s[tid*2], h2b = h2s[tid*2+1];
        const float actv = h2a * sigf(h2b);
        act[bb*2048 + n0 + nlx] = actv;
        Ab[bb*2560 + 512 + n0 + nlx] = bfr(actv);
    }
}

// ---------------------------------------------------------------------------
// K4: final o-update, sync_o, ratings, cert
// ---------------------------------------------------------------------------
__global__ __launch_bounds__(256) void k4_final(
    const float* __restrict__ aoB, const float* __restrict__ boB,
    const float* __restrict__ act, const float* __restrict__ decay_o,
    const int* __restrict__ iol, const int* __restrict__ ior,
    const float* __restrict__ Wout, const float* __restrict__ bout,
    float* __restrict__ out)
{
    __shared__ float sl[2048];
    const int tid = threadIdx.x;
    for (int idx = tid; idx < 2048; idx += 256) {
        const int b = idx >> 6, j = idx & 63;
        const float ro = decf(decay_o[j]);
        const float po = act[b*2048 + iol[j]] * act[b*2048 + ior[j]];
        const float ao = fmaf(ro, aoB[2048 + b*64 + j], po);
        const float bo = fmaf(ro, boB[2048 + b*64 + j], 1.0f);
        const float sv = ao * rsqrtf(bo);
        sl[idx] = sv;
        out[96 + idx] = sv;
    }
    __syncthreads();
    if (tid < 32) {
        float p = bout[0];
        for (int j = 0; j < 64; ++j) p = fmaf(sl[tid*64 + j], Wout[j], p);
        out[tid] = sigf(p);
    } else if (tid < 96) {
        out[32 + (tid - 32)] = ((tid - 32) & 1) ? 1.0f : 0.0f;
    }
}

// ---------------------------------------------------------------------------
extern "C" void kernel_launch(void* const* d_in, const int* in_sizes, int n_in,
                              void* d_out, int out_size, void* d_ws, size_t ws_size,
                              hipStream_t stream)
{
    (void)in_sizes; (void)n_in; (void)out_size;
    const int*   tok   = (const int*)  d_in[0];
    const float* emb   = (const float*)d_in[1];
    const float* st_tr = (const float*)d_in[2];
    const float* st_ac = (const float*)d_in[3];
    const float* dec_a = (const float*)d_in[4];
    const float* dec_o = (const float*)d_in[5];
    const int*   ial   = (const int*)  d_in[6];
    const int*   iar   = (const int*)  d_in[7];
    const int*   iol   = (const int*)  d_in[8];
    const int*   ior   = (const int*)  d_in[9];
    const float* Wq    = (const float*)d_in[10];
    const float* bq    = (const float*)d_in[11];
    const float* Win   = (const float*)d_in[12];
    const float* b_in  = (const float*)d_in[13];
    const float* Wao   = (const float*)d_in[14];
    const float* bao   = (const float*)d_in[15];
    const float* Wsyn  = (const float*)d_in[16];
    const float* bsyn  = (const float*)d_in[17];
    const float* ln_g  = (const float*)d_in[18];
    const float* ln_b  = (const float*)d_in[19];
    const float* W1    = (const float*)d_in[20];
    const float* b1    = (const float*)d_in[21];
    const float* W2    = (const float*)d_in[22];
    const float* b2    = (const float*)d_in[23];
    const float* Wout  = (const float*)d_in[24];
    const float* bout  = (const float*)d_in[25];
    float* out = (float*)d_out;
    char* wsb = (char*)d_ws;
    if (ws_size < (size_t)75761920) return;
    unsigned short* khb  = (unsigned short*)(wsb + 0);          // 16 MB
    unsigned short* vhb  = (unsigned short*)(wsb + 16777216);   // 16 MB
    unsigned short* Wall = (unsigned short*)(wsb + 33554432);   // 20 MB
    unsigned short* W1t  = (unsigned short*)(wsb + 54525952);   // 8 MB
    unsigned short* W2t  = (unsigned short*)(wsb + 62914560);   // 512 KB
    unsigned short* khM  = (unsigned short*)(wsb + 63438848);   // 8 MB
    float* khc  = (float*)(wsb + 71827456);                     // 512 KB
    unsigned short* Mb   = (unsigned short*)(wsb + 72351744);   // 32 KB
    float* qc0  = (float*)(wsb + 72384512);                     // 2 KB
    float* trace = (float*)(wsb + 72386560);                    // 2.5 MB
    float* actb  = (float*)(wsb + 75008000);                    // 256 KB
    float* sg    = (float*)(wsb + 75270144);                    // 256 KB
    unsigned short* Ab = (unsigned short*)(wsb + 75532288);     // 160 KB
    float* aaB   = (float*)(wsb + 75696128);
    float* baB   = (float*)(wsb + 75704320);
    float* aoB   = (float*)(wsb + 75712512);
    float* boB   = (float*)(wsb + 75728896);
    float* bs2   = (float*)(wsb + 75745280);
    float* stats = (float*)(wsb + 75761664);

    k0_init<<<dim3(2841), dim3(256), 0, stream>>>(st_tr, st_ac, iol, ior,
        trace, actb, Ab, aaB, baB, aoB, boB, stats);
    s1_kv_mfma<<<dim3(1024), dim3(256), 0, stream>>>(tok, emb, Win, b_in, khb, vhb);
    s2_wfused<<<dim3(512), dim3(256), 0, stream>>>(Wsyn, Wao, Wall);
    s3_bias<<<dim3(16), dim3(256), 0, stream>>>(Wsyn, bao, bsyn, bs2);
    s4_convsyn<<<dim3(8192), dim3(256), 0, stream>>>(Wsyn, Wall);
    s5_convnlm<<<dim3(1024), dim3(256), 0, stream>>>(W1, b1, W2, W1t, W2t);
    s6a_mproj<<<dim3(8), dim3(256), 0, stream>>>(Win, b_in, Wq, bq, Mb, qc0);
    s6b_khm<<<dim3(512), dim3(256), 0, stream>>>(khb, Mb, qc0, khM, khc);
    for (int u = 0; u < 20; ++u) {
        k1_attn<<<dim3(256), dim3(512), 0, stream>>>(actb, dec_a, dec_o,
            ial, iar, iol, ior, khM, khc, vhb,
            aaB, baB, aoB, boB, Ab, stats, u);
        k2b_syn<<<dim3(256), dim3(512), 0, stream>>>(Ab, Wall, bs2, sg, stats);
        k3_nlm<<<dim3(512), dim3(256), 0, stream>>>(sg, stats, ln_g, ln_b,
            W1t, W2t, b2, trace, actb, Ab, u);
    }
    k4_final<<<dim3(1), dim3(256), 0, stream>>>(aoB, boB, actb, dec_o,
        iol, ior, Wout, bout, out);
}